// Round 12
// baseline (675.046 us; speedup 1.0000x reference)
//
#include <hip/hip_runtime.h>
#include <hip/hip_bf16.h>
#include <math.h>

// ---------------- problem constants ----------------
#define N_RAYS 4096
#define N_SAMPLES 64
#define M_TOTAL (N_RAYS * N_SAMPLES)   // 262144 points
#define MTILE 64                       // points per block (1 ray)
#define NBLK (M_TOTAL / MTILE)         // 4096 blocks
#define THREADS 256                    // 4 FAT waves (64 feats each)

// packed bf16 weight offsets in workspace (elements)
#define OFF_W0 0        // [256][64]   (63 -> pad 64)
#define OFF_W1 16384    // [256][256]
#define OFF_W2 81920
#define OFF_W3 147456
#define OFF_W4 212992   // [256][320]  (k: 256 act + 63 emb + pad)
#define OFF_W5 294912
#define OFF_W6 360448
#define OFF_W7 425984
#define OFF_WF 491520   // feat [256][256]
#define OFF_WD 557056   // dir  [128][288] (k: 256 feat + 27 embd + pad)

typedef __attribute__((ext_vector_type(8))) short bf16x8;
typedef __attribute__((ext_vector_type(4))) float f32x4;
typedef __attribute__((ext_vector_type(4))) unsigned short u16x4;

__device__ __forceinline__ unsigned short f2bf(float f) {
  __hip_bfloat16 h = __float2bfloat16(f);   // HW RNE convert
  return *(unsigned short*)&h;
}
__device__ __forceinline__ float bf2f(unsigned short h) {
  union { unsigned u; float f; } v; v.u = ((unsigned)h) << 16;
  return v.f;
}

// Swizzled LDS element index, f(row)=row&7 (measured best: 3.3e7 conflict cyc
// vs 8.5e7 for the XOR-bit variant). XOR granule 8 elements: b128 reads
// (8-aligned) and b64 writes (4-aligned) stay contiguous within a granule.
template<int STRIDE>
__device__ __forceinline__ int sidx(int r, int c) {
  return r * STRIDE + (c ^ ((r & 7) << 3));
}

// One fused MLP layer: out[64][NW*NFRAG*16] = relu(act . W^T + b), bf16 MFMA.
// TRANSPOSED product (verified R8/R9): acc = mfma(A=W_frag, B=act_frag) so
// D = [feature][point]: col (lane&15) = point, rows = 4 CONSECUTIVE features
// -> epilogue is one 8-byte ds_write_b64 per frag (bank-uniform).
// K = KPAD (from inb, stride SI) + K2 (from emb, stride 64, concat segment).
// FAT-WAVE shape (R11 lesson): NFRAG=4 keeps the R9 per-wave MFMA:overhead
// ratio (128 MFMA/layer) while the 72KB LDS footprint allows 2 blocks/CU.
template<int KPAD, int SI, int K2, int NW, int NFRAG>
__device__ __forceinline__ void layer_mfma(
    const unsigned short* __restrict__ inb,
    const unsigned short* __restrict__ emb,   // concat segment (stride 64) or nullptr
    unsigned short* __restrict__ outb,        // stride 256
    const unsigned short* __restrict__ W,     // packed bf16 [Nout][KPAD+K2]
    const float* __restrict__ bias,
    int wave, int ln15, int lhi)
{
  if (NW < 4 && wave >= NW) return;
  f32x4 acc[4][NFRAG];
#pragma unroll
  for (int m = 0; m < 4; ++m)
#pragma unroll
    for (int n = 0; n < NFRAG; ++n)
      acc[m][n] = (f32x4){0.f, 0.f, 0.f, 0.f};

  const unsigned short* wr[NFRAG];
#pragma unroll
  for (int n = 0; n < NFRAG; ++n)
    wr[n] = W + (wave * (NFRAG * 16) + n * 16 + ln15) * (KPAD + K2) + lhi * 8;

  const int kb = lhi * 8;
#pragma unroll
  for (int k0 = 0; k0 < KPAD; k0 += 32) {
    bf16x8 w[NFRAG];
#pragma unroll
    for (int n = 0; n < NFRAG; ++n)
      w[n] = *(const bf16x8*)(wr[n] + k0);
    bf16x8 a[4];
#pragma unroll
    for (int m = 0; m < 4; ++m)
      a[m] = *(const bf16x8*)(inb + sidx<SI>(m * 16 + ln15, kb + k0));
#pragma unroll
    for (int n = 0; n < NFRAG; ++n)
#pragma unroll
      for (int m = 0; m < 4; ++m)
        acc[m][n] = __builtin_amdgcn_mfma_f32_16x16x32_bf16(w[n], a[m], acc[m][n], 0, 0, 0);
  }
  if (K2 > 0) {
#pragma unroll
    for (int k0 = 0; k0 < K2; k0 += 32) {
      bf16x8 w[NFRAG];
#pragma unroll
      for (int n = 0; n < NFRAG; ++n)
        w[n] = *(const bf16x8*)(wr[n] + KPAD + k0);
      bf16x8 a[4];
#pragma unroll
      for (int m = 0; m < 4; ++m)
        a[m] = *(const bf16x8*)(emb + sidx<64>(m * 16 + ln15, kb + k0));
#pragma unroll
      for (int n = 0; n < NFRAG; ++n)
#pragma unroll
        for (int m = 0; m < 4; ++m)
          acc[m][n] = __builtin_amdgcn_mfma_f32_16x16x32_bf16(w[n], a[m], acc[m][n], 0, 0, 0);
    }
  }

  // epilogue: +bias, relu, f32->bf16, b64 write of 4 consecutive features
#pragma unroll
  for (int n = 0; n < NFRAG; ++n) {
    const int feat0 = wave * (NFRAG * 16) + n * 16 + lhi * 4;
    const f32x4 bb = *(const f32x4*)(bias + feat0);
#pragma unroll
    for (int m = 0; m < 4; ++m) {
      u16x4 pk;
#pragma unroll
      for (int r = 0; r < 4; ++r)
        pk[r] = f2bf(fmaxf(acc[m][n][r] + bb[r], 0.f));
      *(u16x4*)(outb + sidx<256>(m * 16 + ln15, feat0)) = pk;
    }
  }
}

struct NerfArgs {
  const float *sp, *dirs;
  const unsigned short* wp;
  const float *bx0, *bx1, *bx2, *bx3, *bx4, *bx5, *bx6, *bx7;
  const float *bd0, *Wden, *bden, *bfeat, *Wrgb, *brgb;
  float* out;
};

// LDS: buf0[64][256] + buf1[64][256] + embr[64][64] = 72 KB -> 2 blocks/CU
// (147 of 160 KB). 2 blocks x 4 waves = 8 waves/CU (2/SIMD): same wave count
// as R9 but in two INDEPENDENT blocks, so a barrier stalls only half the CU.
// No waves_per_eu attr (R8: explicit (4,4) cut the budget to 64 -> 798 MB
// spills); at 8 waves/CU the implicit budget is 256 VGPRs — no spill risk.
__global__ void __launch_bounds__(THREADS) nerf_main(NerfArgs A) {
  extern __shared__ unsigned short lds[];
  unsigned short* buf0 = lds;                // [64][256]
  unsigned short* buf1 = lds + 64 * 256;     // [64][256]
  unsigned short* embr = lds + 2 * 64 * 256; // [64][64] (emb_x, then emb_d)
  const int tid = threadIdx.x;
  const int wave = tid >> 6, lane = tid & 63;
  const int ln15 = lane & 15, lhi = lane >> 4;
  const int blk = blockIdx.x;

  // ---- harmonic(sample_points) -> embr cols [0..64): sin 0..29, cos 30..59,
  // coords 60..62, col 63 = 0 (pad for W0/W4)
  {
    const int r = tid & 63, g = tid >> 6;   // g = wave; waves 0-2 own coords x/y/z
    if (g < 3) {
      const float x = A.sp[(blk * MTILE + r) * 3 + g];
      embr[sidx<64>(r, 60 + g)] = f2bf(x);
#pragma unroll
      for (int f = 0; f < 10; ++f) {
        const float ar = x * (float)(1 << f);
        embr[sidx<64>(r, g * 10 + f)]      = f2bf(sinf(ar));
        embr[sidx<64>(r, 30 + g * 10 + f)] = f2bf(cosf(ar));
      }
    } else {
      embr[sidx<64>(r, 63)] = 0;
    }
  }
  __syncthreads();

  const unsigned short* wp = A.wp;
  // xyz MLP: L0 reads embr (K=64), then ping-pong buf1<->buf0
  layer_mfma<64, 64, 0, 4, 4>(embr, nullptr, buf1, wp + OFF_W0, A.bx0, wave, ln15, lhi);
  __syncthreads();
  layer_mfma<256, 256, 0, 4, 4>(buf1, nullptr, buf0, wp + OFF_W1, A.bx1, wave, ln15, lhi);
  __syncthreads();
  layer_mfma<256, 256, 0, 4, 4>(buf0, nullptr, buf1, wp + OFF_W2, A.bx2, wave, ln15, lhi);
  __syncthreads();
  layer_mfma<256, 256, 0, 4, 4>(buf1, nullptr, buf0, wp + OFF_W3, A.bx3, wave, ln15, lhi);
  __syncthreads();
  // L4: skip concat [act3 (buf0), emb_x (embr, K2=64)]
  layer_mfma<256, 256, 64, 4, 4>(buf0, embr, buf1, wp + OFF_W4, A.bx4, wave, ln15, lhi);
  __syncthreads();
  layer_mfma<256, 256, 0, 4, 4>(buf1, nullptr, buf0, wp + OFF_W5, A.bx5, wave, ln15, lhi);
  __syncthreads();
  layer_mfma<256, 256, 0, 4, 4>(buf0, nullptr, buf1, wp + OFF_W6, A.bx6, wave, ln15, lhi);
  __syncthreads();
  layer_mfma<256, 256, 0, 4, 4>(buf1, nullptr, buf0, wp + OFF_W7, A.bx7, wave, ln15, lhi);
  __syncthreads();

  // Overlapped phase (single barrier covers all three):
  //  (a) feat layer: buf0(act7) -> buf1
  //  (b) density head: act7 . Wden from buf0 (read-only)
  //  (c) emb_d -> embr cols [0..32) (emb_x dead after L4)
  layer_mfma<256, 256, 0, 4, 4>(buf0, nullptr, buf1, wp + OFF_WF, A.bfeat, wave, ln15, lhi);

  float dens = 0.f;
  {
    const int r = wave * 16 + ln15;
    float s = 0.f;
#pragma unroll
    for (int jj = 0; jj < 8; ++jj) {
      const bf16x8 ch = *(const bf16x8*)(buf0 + sidx<256>(r, lhi * 64 + jj * 8));
#pragma unroll
      for (int e = 0; e < 8; ++e)
        s += bf2f((unsigned short)ch[e]) * A.Wden[lhi * 64 + jj * 8 + e];
    }
    s += __shfl_xor(s, 16);
    s += __shfl_xor(s, 32);
    dens = fmaxf(s + A.bden[0], 0.f);
  }
  {
    // emb_d: sin(12), cos(12), dir(3), pad to 32. 64 rows x 32 cols.
    const float* dp = A.dirs + blk * 3;
    const float d0 = dp[0], d1 = dp[1], d2 = dp[2];
    for (int idx = tid; idx < 64 * 32; idx += THREADS) {
      const int rr = idx >> 5, cc = idx & 31;
      float val = 0.f;
      if (cc < 24) {
        const int j = (cc < 12) ? cc : cc - 12;
        const int d = j >> 2, f = j & 3;
        const float cv = (d == 0 ? d0 : (d == 1 ? d1 : d2)) * (float)(1 << f);
        val = (cc < 12) ? sinf(cv) : cosf(cv);
      } else if (cc < 27) {
        val = (cc == 24) ? d0 : (cc == 25 ? d1 : d2);
      }
      embr[sidx<64>(rr, cc)] = f2bf(val);
    }
  }
  __syncthreads();
  // dir layer: [feat (buf1), emb_d (embr, K2=32)] -> buf0 cols [0..128);
  // 128 outputs across 4 waves (NFRAG=2) — no idle waves
  layer_mfma<256, 256, 32, 4, 2>(buf1, embr, buf0, wp + OFF_WD, A.bd0, wave, ln15, lhi);
  __syncthreads();
  // rgb head: sigmoid(x_dir . Wrgb^T + brgb); fused float4 {dens, rgb} store
  {
    const int r = wave * 16 + ln15;
    float s0 = 0.f, s1 = 0.f, s2 = 0.f;
#pragma unroll
    for (int jj = 0; jj < 4; ++jj) {
      const bf16x8 ch = *(const bf16x8*)(buf0 + sidx<256>(r, lhi * 32 + jj * 8));
#pragma unroll
      for (int e = 0; e < 8; ++e) {
        const int k = lhi * 32 + jj * 8 + e;
        const float xv = bf2f((unsigned short)ch[e]);
        s0 += xv * A.Wrgb[k];
        s1 += xv * A.Wrgb[128 + k];
        s2 += xv * A.Wrgb[256 + k];
      }
    }
    s0 += __shfl_xor(s0, 16); s0 += __shfl_xor(s0, 32);
    s1 += __shfl_xor(s1, 16); s1 += __shfl_xor(s1, 32);
    s2 += __shfl_xor(s2, 16); s2 += __shfl_xor(s2, 32);
    if (lhi == 0) {
      f32x4 o;
      o[0] = dens;
      o[1] = 1.f / (1.f + expf(-(s0 + A.brgb[0])));
      o[2] = 1.f / (1.f + expf(-(s1 + A.brgb[1])));
      o[3] = 1.f / (1.f + expf(-(s2 + A.brgb[2])));
      *(f32x4*)(A.out + (blk * MTILE + r) * 4) = o;
    }
  }
}

// ---------------- weight packing prologue (fp32 -> bf16, K padded) ----------------
struct PackDesc { const float* src; int out_dim, in_dim, kpad, dst_off; };
struct PackArgs { PackDesc d[10]; };

__global__ void __launch_bounds__(256) pack_weights(PackArgs P, unsigned short* dst) {
  const PackDesc pd = P.d[blockIdx.y];
  const int idx = blockIdx.x * 256 + threadIdx.x;
  const int tot = pd.out_dim * pd.kpad;
  if (idx >= tot) return;
  const int o = idx / pd.kpad;
  const int k = idx - o * pd.kpad;
  const float v = (k < pd.in_dim) ? pd.src[o * pd.in_dim + k] : 0.f;
  dst[pd.dst_off + idx] = f2bf(v);
}

extern "C" void kernel_launch(void* const* d_in, const int* in_sizes, int n_in,
                              void* d_out, int out_size, void* d_ws, size_t ws_size,
                              hipStream_t stream) {
  unsigned short* wpack = (unsigned short*)d_ws;

  const float* Wx[8]; const float* bx[8];
  for (int i = 0; i < 8; ++i) {
    Wx[i] = (const float*)d_in[2 + 2 * i];
    bx[i] = (const float*)d_in[3 + 2 * i];
  }

  PackArgs P;
  P.d[0] = { Wx[0], 256, 63, 64, OFF_W0 };
  P.d[1] = { Wx[1], 256, 256, 256, OFF_W1 };
  P.d[2] = { Wx[2], 256, 256, 256, OFF_W2 };
  P.d[3] = { Wx[3], 256, 256, 256, OFF_W3 };
  P.d[4] = { Wx[4], 256, 319, 320, OFF_W4 };
  P.d[5] = { Wx[5], 256, 256, 256, OFF_W5 };
  P.d[6] = { Wx[6], 256, 256, 256, OFF_W6 };
  P.d[7] = { Wx[7], 256, 256, 256, OFF_W7 };
  P.d[8] = { (const float*)d_in[22], 256, 256, 256, OFF_WF };  // Wfeat
  P.d[9] = { (const float*)d_in[18], 128, 283, 288, OFF_WD };  // Wd0
  hipLaunchKernelGGL(pack_weights, dim3(320, 10), dim3(256), 0, stream, P, wpack);

  NerfArgs A;
  A.sp = (const float*)d_in[0];
  A.dirs = (const float*)d_in[1];
  A.wp = wpack;
  A.bx0 = bx[0]; A.bx1 = bx[1]; A.bx2 = bx[2]; A.bx3 = bx[3];
  A.bx4 = bx[4]; A.bx5 = bx[5]; A.bx6 = bx[6]; A.bx7 = bx[7];
  A.bd0 = (const float*)d_in[19];
  A.Wden = (const float*)d_in[20];
  A.bden = (const float*)d_in[21];
  A.bfeat = (const float*)d_in[23];
  A.Wrgb = (const float*)d_in[24];
  A.brgb = (const float*)d_in[25];
  A.out = (float*)d_out;

  const int lds_bytes = (2 * 64 * 256 + 64 * 64) * 2;  // 73728 B -> 2 blocks/CU
  hipFuncSetAttribute((const void*)nerf_main, hipFuncAttributeMaxDynamicSharedMemorySize, lds_bytes);
  hipLaunchKernelGGL(nerf_main, dim3(NBLK), dim3(THREADS), lds_bytes, stream, A);
}

// Round 15
// 503.260 us; speedup vs baseline: 1.3413x; 1.3413x over previous
//
#include <hip/hip_runtime.h>
#include <hip/hip_bf16.h>
#include <math.h>

// ---------------- problem constants ----------------
#define N_RAYS 4096
#define N_SAMPLES 64
#define M_TOTAL (N_RAYS * N_SAMPLES)   // 262144 points
#define MTILE 128                      // points per block (2 rays) — R9-proven optimum
#define NBLK (M_TOTAL / MTILE)         // 2048 blocks
#define THREADS 512                    // 8 fat waves (32 feats x 128 pts each)

// packed bf16 weight offsets in workspace (elements)
#define OFF_W0 0        // [256][64]   (63 -> pad 64)
#define OFF_W1 16384    // [256][256]
#define OFF_W2 81920
#define OFF_W3 147456
#define OFF_W4 212992   // [256][320]  (k: 256 act + 63 emb + 1 pad)
#define OFF_W5 294912
#define OFF_W6 360448
#define OFF_W7 425984
#define OFF_WF 491520   // feat [256][256]
#define OFF_WD 557056   // dir  [128][288] (k: 256 feat + 27 embd + 5 pad)

typedef __attribute__((ext_vector_type(8))) short bf16x8;
typedef __attribute__((ext_vector_type(4))) float f32x4;
typedef __attribute__((ext_vector_type(4))) unsigned short u16x4;

__device__ __forceinline__ unsigned short f2bf(float f) {
  __hip_bfloat16 h = __float2bfloat16(f);   // HW RNE convert
  return *(unsigned short*)&h;
}
__device__ __forceinline__ float bf2f(unsigned short h) {
  union { unsigned u; float f; } v; v.u = ((unsigned)h) << 16;
  return v.f;
}

// Swizzled LDS element index, f(row)=row&7 (measured best: 3.3e7 conflict cyc
// vs 8.5e7 for the XOR-bit variant). XOR granule 8 elements: b128 reads
// (8-aligned) and b64 writes (4-aligned) stay contiguous within a granule.
template<int STRIDE>
__device__ __forceinline__ int sidx(int r, int c) {
  return r * STRIDE + (c ^ ((r & 7) << 3));
}

// One fused MLP layer: out[128][NF*16*8] = relu(act . W^T + b), bf16 MFMA.
// TRANSPOSED product (verified R8/R9): acc = mfma(A=W_frag, B=act_frag) so
// D = [feature][point]: col (lane&15) = point, rows = 4 CONSECUTIVE features
// -> epilogue is one 8-byte ds_write_b64 per frag (bank-uniform).
// K = KPAD (inb, stride 256) + K2 (emb, STRIDE 64 — the ONLY path that may
// read embr; R13 bug: L0 passed embr as inb and was read at stride 256).
// Per wave: 8 point-frags (2 reg-diet groups of 4) x NF feature-frags.
template<int KPAD, int K2, int NF>
__device__ __forceinline__ void layer_mfma(
    const unsigned short* __restrict__ inb,   // stride 256 (ignored if KPAD==0)
    const unsigned short* __restrict__ emb,   // stride 64 concat segment or nullptr
    unsigned short* __restrict__ outb,        // stride 256
    const unsigned short* __restrict__ W,     // packed bf16 [Nout][KPAD+K2]
    const float* __restrict__ bias,
    int wave, int ln15, int lhi)
{
  f32x4 acc[8][NF];
#pragma unroll
  for (int m = 0; m < 8; ++m)
#pragma unroll
    for (int n = 0; n < NF; ++n)
      acc[m][n] = (f32x4){0.f, 0.f, 0.f, 0.f};

  const unsigned short* wr[NF];
#pragma unroll
  for (int n = 0; n < NF; ++n)
    wr[n] = W + (wave * (NF * 16) + n * 16 + ln15) * (KPAD + K2) + lhi * 8;

  const int kb = lhi * 8;
#pragma unroll
  for (int k0 = 0; k0 < KPAD; k0 += 32) {
    bf16x8 w[NF];
#pragma unroll
    for (int n = 0; n < NF; ++n)
      w[n] = *(const bf16x8*)(wr[n] + k0);
#pragma unroll
    for (int g = 0; g < 2; ++g) {
      bf16x8 a[4];
#pragma unroll
      for (int mm = 0; mm < 4; ++mm)
        a[mm] = *(const bf16x8*)(inb + sidx<256>((g * 4 + mm) * 16 + ln15, kb + k0));
#pragma unroll
      for (int n = 0; n < NF; ++n)
#pragma unroll
        for (int mm = 0; mm < 4; ++mm)
          acc[g * 4 + mm][n] =
              __builtin_amdgcn_mfma_f32_16x16x32_bf16(w[n], a[mm], acc[g * 4 + mm][n], 0, 0, 0);
    }
  }
  if (K2 > 0) {
#pragma unroll
    for (int k0 = 0; k0 < K2; k0 += 32) {
      bf16x8 w[NF];
#pragma unroll
      for (int n = 0; n < NF; ++n)
        w[n] = *(const bf16x8*)(wr[n] + KPAD + k0);
#pragma unroll
      for (int g = 0; g < 2; ++g) {
        bf16x8 a[4];
#pragma unroll
        for (int mm = 0; mm < 4; ++mm)
          a[mm] = *(const bf16x8*)(emb + sidx<64>((g * 4 + mm) * 16 + ln15, kb + k0));
#pragma unroll
        for (int n = 0; n < NF; ++n)
#pragma unroll
          for (int mm = 0; mm < 4; ++mm)
            acc[g * 4 + mm][n] =
                __builtin_amdgcn_mfma_f32_16x16x32_bf16(w[n], a[mm], acc[g * 4 + mm][n], 0, 0, 0);
      }
    }
  }

  // epilogue: +bias, relu, f32->bf16, b64 write of 4 consecutive features
#pragma unroll
  for (int n = 0; n < NF; ++n) {
    const int feat0 = wave * (NF * 16) + n * 16 + lhi * 4;
    const f32x4 bb = *(const f32x4*)(bias + feat0);
#pragma unroll
    for (int m = 0; m < 8; ++m) {
      u16x4 pk;
#pragma unroll
      for (int r = 0; r < 4; ++r)
        pk[r] = f2bf(fmaxf(acc[m][n][r] + bb[r], 0.f));
      *(u16x4*)(outb + sidx<256>(m * 16 + ln15, feat0)) = pk;
    }
  }
}

struct NerfArgs {
  const float *sp, *dirs;
  const unsigned short* wp;
  const float *bx0, *bx1, *bx2, *bx3, *bx4, *bx5, *bx6, *bx7;
  const float *bd0, *Wden, *bden, *bfeat, *Wrgb, *brgb;
  float* out;
};

// LDS: buf0[128][256] + buf1[128][256] + embr[128][64] = 144 KB, 1 block/CU.
// Pin exactly 2 waves/EU (the LDS-capped occupancy) so the allocator uses the
// full register budget — R9-proven: VGPR=100, zero spills, best time (432us).
// (R8's waves_per_eu(4,4) cut the budget to 64 -> 798 MB spill traffic;
//  MTILE=64 variants R10-R12 all lost to per-block fixed costs.)
__global__ void __attribute__((amdgpu_flat_work_group_size(THREADS, THREADS),
                               amdgpu_waves_per_eu(2, 2)))
nerf_main(NerfArgs A) {
  extern __shared__ unsigned short lds[];
  unsigned short* buf0 = lds;                 // [128][256]
  unsigned short* buf1 = lds + 128 * 256;     // [128][256]
  unsigned short* embr = lds + 2 * 128 * 256; // [128][64] (emb_x, then emb_d)
  const int tid = threadIdx.x;
  const int wave = tid >> 6, lane = tid & 63;
  const int ln15 = lane & 15, lhi = lane >> 4;
  const int blk = blockIdx.x;

  // ---- harmonic(sample_points) -> embr cols [0..64): sin 0..29, cos 30..59,
  // coords 60..62, col 63 = 0 (pad for W0/W4)
  {
    const int r = tid & 127, g = tid >> 7;   // g: coord x/y/z for g<3
    if (g < 3) {
      const float x = A.sp[(blk * MTILE + r) * 3 + g];
      embr[sidx<64>(r, 60 + g)] = f2bf(x);
#pragma unroll
      for (int f = 0; f < 10; ++f) {
        const float ar = x * (float)(1 << f);
        embr[sidx<64>(r, g * 10 + f)]      = f2bf(sinf(ar));
        embr[sidx<64>(r, 30 + g * 10 + f)] = f2bf(cosf(ar));
      }
    } else {
      embr[sidx<64>(r, 63)] = 0;
    }
  }
  __syncthreads();

  const unsigned short* wp = A.wp;
  // L0: K=64 entirely from embr via the K2 path (stride 64!) — R13 bug fix.
  layer_mfma<0, 64, 2>(buf0, embr, buf1, wp + OFF_W0, A.bx0, wave, ln15, lhi);
  __syncthreads();
  layer_mfma<256, 0, 2>(buf1, nullptr, buf0, wp + OFF_W1, A.bx1, wave, ln15, lhi);
  __syncthreads();
  layer_mfma<256, 0, 2>(buf0, nullptr, buf1, wp + OFF_W2, A.bx2, wave, ln15, lhi);
  __syncthreads();
  layer_mfma<256, 0, 2>(buf1, nullptr, buf0, wp + OFF_W3, A.bx3, wave, ln15, lhi);
  __syncthreads();
  // L4: skip concat [act3 (buf0, stride 256), emb_x (embr, K2=64, stride 64)]
  layer_mfma<256, 64, 2>(buf0, embr, buf1, wp + OFF_W4, A.bx4, wave, ln15, lhi);
  __syncthreads();
  layer_mfma<256, 0, 2>(buf1, nullptr, buf0, wp + OFF_W5, A.bx5, wave, ln15, lhi);
  __syncthreads();
  layer_mfma<256, 0, 2>(buf0, nullptr, buf1, wp + OFF_W6, A.bx6, wave, ln15, lhi);
  __syncthreads();
  layer_mfma<256, 0, 2>(buf1, nullptr, buf0, wp + OFF_W7, A.bx7, wave, ln15, lhi);
  __syncthreads();

  // Overlapped tail phase (single barrier covers all three):
  //  (a) feat layer: buf0(act7) -> buf1
  //  (b) density head: act7 . Wden from buf0 (read-only), kept in-register
  //  (c) emb_d -> embr cols [0..32) (emb_x dead after L4)
  layer_mfma<256, 0, 2>(buf0, nullptr, buf1, wp + OFF_WF, A.bfeat, wave, ln15, lhi);

  float dens = 0.f;
  {
    const int r = wave * 16 + ln15;
    float s = 0.f;
#pragma unroll
    for (int jj = 0; jj < 8; ++jj) {
      const bf16x8 ch = *(const bf16x8*)(buf0 + sidx<256>(r, lhi * 64 + jj * 8));
#pragma unroll
      for (int e = 0; e < 8; ++e)
        s += bf2f((unsigned short)ch[e]) * A.Wden[lhi * 64 + jj * 8 + e];
    }
    s += __shfl_xor(s, 16);
    s += __shfl_xor(s, 32);
    dens = fmaxf(s + A.bden[0], 0.f);
  }
  {
    // emb_d: sin(12), cos(12), dir(3), pad to 32. 128 rows (2 rays) x 32 cols.
    const float* dp = A.dirs + blk * 2 * 3;
    const float dx[2] = {dp[0], dp[3]}, dy[2] = {dp[1], dp[4]}, dz[2] = {dp[2], dp[5]};
    for (int idx = tid; idx < 128 * 32; idx += THREADS) {
      const int rr = idx >> 5, cc = idx & 31, h = rr >> 6;
      float val = 0.f;
      if (cc < 24) {
        const int j = (cc < 12) ? cc : cc - 12;
        const int d = j >> 2, f = j & 3;
        const float cv = (d == 0 ? dx[h] : (d == 1 ? dy[h] : dz[h])) * (float)(1 << f);
        val = (cc < 12) ? sinf(cv) : cosf(cv);
      } else if (cc < 27) {
        val = (cc == 24) ? dx[h] : (cc == 25 ? dy[h] : dz[h]);
      }
      embr[sidx<64>(rr, cc)] = f2bf(val);
    }
  }
  __syncthreads();
  // dir layer: [feat (buf1), emb_d (embr, K2=32)] -> buf0 cols [0..128);
  // NF=1: 8 waves x 16 feats = 128 outputs
  layer_mfma<256, 32, 1>(buf1, embr, buf0, wp + OFF_WD, A.bd0, wave, ln15, lhi);
  __syncthreads();
  // rgb head: sigmoid(x_dir . Wrgb^T + brgb); fused float4 {dens, rgb} store
  {
    const int r = wave * 16 + ln15;
    float s0 = 0.f, s1 = 0.f, s2 = 0.f;
#pragma unroll
    for (int jj = 0; jj < 4; ++jj) {
      const bf16x8 ch = *(const bf16x8*)(buf0 + sidx<256>(r, lhi * 32 + jj * 8));
#pragma unroll
      for (int e = 0; e < 8; ++e) {
        const int k = lhi * 32 + jj * 8 + e;
        const float xv = bf2f((unsigned short)ch[e]);
        s0 += xv * A.Wrgb[k];
        s1 += xv * A.Wrgb[128 + k];
        s2 += xv * A.Wrgb[256 + k];
      }
    }
    s0 += __shfl_xor(s0, 16); s0 += __shfl_xor(s0, 32);
    s1 += __shfl_xor(s1, 16); s1 += __shfl_xor(s1, 32);
    s2 += __shfl_xor(s2, 16); s2 += __shfl_xor(s2, 32);
    if (lhi == 0) {
      f32x4 o;
      o[0] = dens;
      o[1] = 1.f / (1.f + expf(-(s0 + A.brgb[0])));
      o[2] = 1.f / (1.f + expf(-(s1 + A.brgb[1])));
      o[3] = 1.f / (1.f + expf(-(s2 + A.brgb[2])));
      *(f32x4*)(A.out + (blk * MTILE + r) * 4) = o;
    }
  }
}

// ---------------- weight packing prologue (fp32 -> bf16, K padded) ----------------
struct PackDesc { const float* src; int out_dim, in_dim, kpad, dst_off; };
struct PackArgs { PackDesc d[10]; };

__global__ void __launch_bounds__(256) pack_weights(PackArgs P, unsigned short* dst) {
  const PackDesc pd = P.d[blockIdx.y];
  const int idx = blockIdx.x * 256 + threadIdx.x;
  const int tot = pd.out_dim * pd.kpad;
  if (idx >= tot) return;
  const int o = idx / pd.kpad;
  const int k = idx - o * pd.kpad;
  const float v = (k < pd.in_dim) ? pd.src[o * pd.in_dim + k] : 0.f;
  dst[pd.dst_off + idx] = f2bf(v);
}

extern "C" void kernel_launch(void* const* d_in, const int* in_sizes, int n_in,
                              void* d_out, int out_size, void* d_ws, size_t ws_size,
                              hipStream_t stream) {
  unsigned short* wpack = (unsigned short*)d_ws;

  const float* Wx[8]; const float* bx[8];
  for (int i = 0; i < 8; ++i) {
    Wx[i] = (const float*)d_in[2 + 2 * i];
    bx[i] = (const float*)d_in[3 + 2 * i];
  }

  PackArgs P;
  P.d[0] = { Wx[0], 256, 63, 64, OFF_W0 };
  P.d[1] = { Wx[1], 256, 256, 256, OFF_W1 };
  P.d[2] = { Wx[2], 256, 256, 256, OFF_W2 };
  P.d[3] = { Wx[3], 256, 256, 256, OFF_W3 };
  P.d[4] = { Wx[4], 256, 319, 320, OFF_W4 };
  P.d[5] = { Wx[5], 256, 256, 256, OFF_W5 };
  P.d[6] = { Wx[6], 256, 256, 256, OFF_W6 };
  P.d[7] = { Wx[7], 256, 256, 256, OFF_W7 };
  P.d[8] = { (const float*)d_in[22], 256, 256, 256, OFF_WF };  // Wfeat
  P.d[9] = { (const float*)d_in[18], 128, 283, 288, OFF_WD };  // Wd0
  hipLaunchKernelGGL(pack_weights, dim3(320, 10), dim3(256), 0, stream, P, wpack);

  NerfArgs A;
  A.sp = (const float*)d_in[0];
  A.dirs = (const float*)d_in[1];
  A.wp = wpack;
  A.bx0 = bx[0]; A.bx1 = bx[1]; A.bx2 = bx[2]; A.bx3 = bx[3];
  A.bx4 = bx[4]; A.bx5 = bx[5]; A.bx6 = bx[6]; A.bx7 = bx[7];
  A.bd0 = (const float*)d_in[19];
  A.Wden = (const float*)d_in[20];
  A.bden = (const float*)d_in[21];
  A.bfeat = (const float*)d_in[23];
  A.Wrgb = (const float*)d_in[24];
  A.brgb = (const float*)d_in[25];
  A.out = (float*)d_out;

  const int lds_bytes = (2 * 128 * 256 + 128 * 64) * 2;  // 147456 B, 1 block/CU
  hipFuncSetAttribute((const void*)nerf_main, hipFuncAttributeMaxDynamicSharedMemorySize, lds_bytes);
  hipLaunchKernelGGL(nerf_main, dim3(NBLK), dim3(THREADS), lds_bytes, stream, A);
}